// Round 4
// baseline (376.314 us; speedup 1.0000x reference)
//
#include <hip/hip_runtime.h>
#include <hip/hip_bf16.h>
#include <math.h>

#define N_NODES 200000
#define E_DIM   128
#define B_EDGES 4096
#define H_NBRS  20
#define NEG_K   5
#define HID     60
#define Z_ROW   (N_NODES + 3)   // all-zero bf16 row in embH

typedef short bf16x8 __attribute__((ext_vector_type(8)));
typedef float f32x4  __attribute__((ext_vector_type(4)));

#define MFMA(a, b, c) __builtin_amdgcn_mfma_f32_16x16x32_bf16((a), (b), (c), 0, 0, 0)

__device__ __forceinline__ unsigned short f2b(float f) {  // fp32 -> bf16 RNE
  unsigned u = __float_as_uint(f);
  u += 0x7fffu + ((u >> 16) & 1u);
  return (unsigned short)(u >> 16);
}

__device__ __forceinline__ float wave_sum(float v) {
  #pragma unroll
  for (int m = 1; m < 64; m <<= 1) v += __shfl_xor(v, m, 64);
  return v;
}
__device__ __forceinline__ float wave_max(float v) {
  #pragma unroll
  for (int m = 1; m < 64; m <<= 1) v = fmaxf(v, __shfl_xor(v, m, 64));
  return v;
}

// XOR-swizzled bf16 tile: row stride 128 bf16 (256B); 16B chunk index is
// XORed with (row&3)<<2 so ds_read_b128 A/B-fragment reads spread banks.
__device__ __forceinline__ bf16x8 xfrag(const unsigned short* xS, int m, int kk, int q) {
  int chunk = (kk * 4 + q) ^ ((m & 3) << 2);
  return *(const bf16x8*)(xS + m * 128 + chunk * 8);
}

// ---------------------------------------------------------------------------
// prep: pack W1/W2 into MFMA B-fragment order (bf16); wa1=W@a1, wa2=W@a2,
// wgw=W@gw (f32 + bf16 rows N_NODES..N_NODES+2 of embH, zero row N_NODES+3);
// zero the loss slot.
// ---------------------------------------------------------------------------
__global__ __launch_bounds__(1024) void prep_kernel(
    const float* __restrict__ W, const float* __restrict__ a,
    const float* __restrict__ gw, const float* __restrict__ W1,
    const float* __restrict__ W2, unsigned short* __restrict__ w1f,
    unsigned short* __restrict__ w2f, float* __restrict__ wav,
    unsigned short* __restrict__ embH, float* __restrict__ out_loss) {
  __shared__ float wavS[3 * E_DIM];
  const int tid = threadIdx.x;
  const int lane = tid & 63, grp = tid >> 6;  // 16 groups of 64 lanes
  const int q = lane >> 4, c = lane & 15;

  {  // W1 [128x60] -> frags g = kk*4 + t  (4 ksteps x 4 n-tiles, n padded to 64)
    const int kk = grp >> 2, t = grp & 3;
    const int n = t * 16 + c, k0 = kk * 32 + q * 8;
    unsigned v[4];
    #pragma unroll
    for (int jj = 0; jj < 4; ++jj) {
      unsigned short lo = (n < 60) ? f2b(W1[(k0 + 2 * jj) * 60 + n]) : 0;
      unsigned short hi = (n < 60) ? f2b(W1[(k0 + 2 * jj + 1) * 60 + n]) : 0;
      v[jj] = (unsigned)lo | ((unsigned)hi << 16);
    }
    ((uint4*)w1f)[grp * 64 + lane] = make_uint4(v[0], v[1], v[2], v[3]);
  }
  {  // W2 [60x128] -> frags g = ks*8 + t  (2 ksteps (K padded 60->64) x 8 n-tiles)
    const int ks = grp >> 3, t = grp & 7;
    const int n = t * 16 + c, k0 = ks * 32 + q * 8;
    unsigned v[4];
    #pragma unroll
    for (int jj = 0; jj < 4; ++jj) {
      int k = k0 + 2 * jj;
      unsigned short lo = (k < 60) ? f2b(W2[k * 128 + n]) : 0;
      unsigned short hi = (k + 1 < 60) ? f2b(W2[(k + 1) * 128 + n]) : 0;
      v[jj] = (unsigned)lo | ((unsigned)hi << 16);
    }
    ((uint4*)w2f)[grp * 64 + lane] = make_uint4(v[0], v[1], v[2], v[3]);
  }
  if (tid < 128) {
    const float* row = W + tid * E_DIM;
    float s1 = 0.f, s2 = 0.f, sg = 0.f;
    for (int f = 0; f < E_DIM; ++f) {
      float w = row[f];
      s1 = fmaf(w, a[f], s1);
      s2 = fmaf(w, a[E_DIM + f], s2);
      sg = fmaf(w, gw[f], sg);
    }
    wav[tid] = s1; wav[E_DIM + tid] = s2; wav[2 * E_DIM + tid] = sg;
    wavS[tid] = s1; wavS[E_DIM + tid] = s2; wavS[2 * E_DIM + tid] = sg;
  }
  __syncthreads();
  if (embH && tid < 512) {
    int r = tid >> 7, col = tid & 127;
    embH[(size_t)(N_NODES + r) * E_DIM + col] = (r < 3) ? f2b(wavS[r * E_DIM + col]) : 0;
  }
  if (tid == 0) *out_loss = 0.f;
}

// ---------------------------------------------------------------------------
// MLP via MFMA: emb = relu(nf@W1+b1)@W2+b2. Block = 64 rows, wave = 16 rows.
// Wave-private LDS tiles -> no __syncthreads. Optionally also writes a bf16
// copy (embH) for the edge kernel's gathers; f32 emb stores go nontemporal
// then so the 51MB bf16 copy stays L3-resident.
// ---------------------------------------------------------------------------
__global__ __launch_bounds__(256) void mlp_kernel(
    const float* __restrict__ nf, const unsigned short* __restrict__ w1f,
    const unsigned short* __restrict__ w2f, const float* __restrict__ b1,
    const float* __restrict__ b2, float* __restrict__ emb,
    unsigned short* __restrict__ embH) {
  __shared__ unsigned short aS[4][16 * 128];  // per-wave A tile (bf16, swizzled)
  __shared__ float cS[4][16 * 68];            // per-wave hidden tile (f32, stride 68)

  const int tid = threadIdx.x, wave = tid >> 6, lane = tid & 63;
  const int q = lane >> 4, c = lane & 15;
  unsigned short* aw = aS[wave];
  float* cw = cS[wave];
  const size_t R = (size_t)blockIdx.x * 64 + wave * 16;  // 3125*64 == 200000 exactly

  // stage 16 rows x 128 f32 -> bf16 swizzled LDS (8 float4 per lane)
  #pragma unroll
  for (int it = 0; it < 8; ++it) {
    int v = it * 64 + lane;          // 0..511
    int r = v >> 5, c4 = v & 31;
    float4 x = *(const float4*)(nf + (R + r) * E_DIM + c4 * 4);
    int chunk = c4 >> 1, half = c4 & 1;
    int phys = r * 128 + (((chunk ^ ((r & 3) << 2))) << 3) + (half << 2);
    *(ushort4*)&aw[phys] = make_ushort4(f2b(x.x), f2b(x.y), f2b(x.z), f2b(x.w));
  }

  // layer 1: C1[16x64] = A[16x128] @ W1[128x64]
  bf16x8 w1[16];
  #pragma unroll
  for (int g = 0; g < 16; ++g) w1[g] = *(const bf16x8*)(w1f + (g * 64 + lane) * 8);

  f32x4 acc1[4] = {};
  #pragma unroll
  for (int kk = 0; kk < 4; ++kk) {
    bf16x8 av = xfrag(aw, c, kk, q);  // A: m = lane&15, k = kk*32 + q*8 + j
    #pragma unroll
    for (int t = 0; t < 4; ++t) acc1[t] = MFMA(av, w1[kk * 4 + t], acc1[t]);
  }
  // bias + relu -> cS (C/D layout: row = q*4+i, col = lane&15 within tile)
  #pragma unroll
  for (int t = 0; t < 4; ++t) {
    int n = t * 16 + c;
    float bv = (n < 60) ? b1[n] : 0.f;
    #pragma unroll
    for (int i = 0; i < 4; ++i)
      cw[(q * 4 + i) * 68 + n] = fmaxf(acc1[t][i] + bv, 0.f);
  }

  // A2 frags from cS: row m = lane&15, k = ks*32 + q*8 + j
  bf16x8 a2[2];
  #pragma unroll
  for (int ks = 0; ks < 2; ++ks) {
    f32x4 r0 = *(const f32x4*)&cw[c * 68 + ks * 32 + q * 8];
    f32x4 r1 = *(const f32x4*)&cw[c * 68 + ks * 32 + q * 8 + 4];
    bf16x8 t8;
    #pragma unroll
    for (int j = 0; j < 4; ++j) {
      t8[j] = (short)f2b(r0[j]);
      t8[4 + j] = (short)f2b(r1[j]);
    }
    a2[ks] = t8;
  }

  // layer 2: emb[16x128] = relu(C1)[16x64] @ W2[64x128]
  bf16x8 w2r[16];
  #pragma unroll
  for (int g = 0; g < 16; ++g) w2r[g] = *(const bf16x8*)(w2f + (g * 64 + lane) * 8);

  f32x4 acc2[8] = {};
  #pragma unroll
  for (int ks = 0; ks < 2; ++ks)
    #pragma unroll
    for (int t = 0; t < 8; ++t) acc2[t] = MFMA(a2[ks], w2r[ks * 8 + t], acc2[t]);

  if (embH) {
    #pragma unroll
    for (int t = 0; t < 8; ++t) {
      int n = t * 16 + c;
      float bv = b2[n];
      #pragma unroll
      for (int i = 0; i < 4; ++i) {
        float val = acc2[t][i] + bv;
        __builtin_nontemporal_store(val, &emb[(R + q * 4 + i) * E_DIM + n]);
        embH[(R + q * 4 + i) * E_DIM + n] = f2b(val);
      }
    }
  } else {
    #pragma unroll
    for (int t = 0; t < 8; ++t) {
      int n = t * 16 + c;
      float bv = b2[n];
      #pragma unroll
      for (int i = 0; i < 4; ++i)
        emb[(R + q * 4 + i) * E_DIM + n] = acc2[t][i] + bv;
    }
  }
}

// ---------------------------------------------------------------------------
// Edge kernel: one block per edge. X[64x128] (bf16):
//   0=pos0, 1=pos1, 2..6=neg0, 7..11=neg1, 12=wa1, 13=wa2, 14=wgw, 15=0,
//   16..35=s_h, 36..55=t_h, 56..63=0.
// Only Gram cols 0..15 + diagonals are ever used: each wave computes its
// 16x16 tile vs cols 0..15 (gA, stride 17) and its diagonal tile
// (B-frag == A-frag -> MFMA(av,av)) for diagS. 8 MFMA/wave, 21.5KB LDS.
// S[]: 0..19 c2_s, 20..39 c2_t, 40 P_s, 41 P_t, 42 glogit_s, 43 glogit_t.
// ---------------------------------------------------------------------------
__global__ __launch_bounds__(256) void edge_kernel(
    const float* __restrict__ emb, const unsigned short* __restrict__ embH,
    const int* __restrict__ sources, const int* __restrict__ destinations,
    const float* __restrict__ e_times,
    const int* __restrict__ s_h_nodes, const int* __restrict__ t_h_nodes,
    const float* __restrict__ s_h_times, const float* __restrict__ t_h_times,
    const float* __restrict__ s_maskp, const float* __restrict__ t_maskp,
    const int* __restrict__ neg_src, const int* __restrict__ neg_dst,
    const float* __restrict__ wav,
    const float* __restrict__ delta_s_p, const float* __restrict__ delta_t_p,
    const float* __restrict__ gbp,
    float* __restrict__ out_loss, float* __restrict__ out_pos) {
  __shared__ unsigned short xS[64 * 128];  // 16 KB bf16 swizzled
  __shared__ float gA[64 * 17];            // Gram cols 0..15, stride 17
  __shared__ float diagS[64];
  __shared__ float S[64];
  __shared__ int rows[64];

  const int b = blockIdx.x;
  const int tid = threadIdx.x;
  const int wave = tid >> 6, lane = tid & 63;
  const int q = lane >> 4, c = lane & 15;

  if (tid < 64) {
    int idx = Z_ROW;
    if (tid == 0)       idx = sources[b];
    else if (tid == 1)  idx = destinations[b];
    else if (tid < 7)   idx = neg_src[b * NEG_K + (tid - 2)];
    else if (tid < 12)  idx = neg_dst[b * NEG_K + (tid - 7)];
    else if (tid == 12) idx = N_NODES;
    else if (tid == 13) idx = N_NODES + 1;
    else if (tid == 14) idx = N_NODES + 2;
    else if (tid >= 16 && tid < 36) idx = s_h_nodes[b * H_NBRS + (tid - 16)];
    else if (tid >= 36 && tid < 56) idx = t_h_nodes[b * H_NBRS + (tid - 36)];
    rows[tid] = idx;
  }
  __syncthreads();

  if (embH) {
    // bf16 gather: 64 rows x 256B = 1024 16B-chunks over 256 threads
    #pragma unroll
    for (int it = 0; it < 4; ++it) {
      int v = it * 256 + tid;
      int r = v >> 4, ch = v & 15;
      uint4 u = *(const uint4*)(embH + (size_t)rows[r] * E_DIM + ch * 8);
      int phys = ch ^ ((r & 3) << 2);
      *(uint4*)&xS[r * 128 + phys * 8] = u;
    }
  } else {
    #pragma unroll
    for (int it = 0; it < 8; ++it) {
      int v = it * 256 + tid;
      int r = v >> 5, c4 = v & 31;
      float4 x = make_float4(0.f, 0.f, 0.f, 0.f);
      if (r < 12 || (r >= 16 && r < 56))
        x = *(const float4*)(emb + (size_t)rows[r] * E_DIM + c4 * 4);
      else if (r >= 12 && r < 15)
        x = *(const float4*)(wav + (r - 12) * E_DIM + c4 * 4);
      int chunk = c4 >> 1, half = c4 & 1;
      int phys = r * 128 + ((chunk ^ ((r & 3) << 2)) << 3) + (half << 2);
      *(ushort4*)&xS[phys] = make_ushort4(f2b(x.x), f2b(x.y), f2b(x.z), f2b(x.w));
    }
  }
  __syncthreads();

  // Gram: wave w -> rows [16w,16w+16) x cols [0,16) (accA) + own diag (accB)
  {
    f32x4 accA = {0.f, 0.f, 0.f, 0.f};
    f32x4 accB = {0.f, 0.f, 0.f, 0.f};
    #pragma unroll
    for (int kk = 0; kk < 4; ++kk) {
      bf16x8 av = xfrag(xS, wave * 16 + c, kk, q);
      bf16x8 b0 = xfrag(xS, c, kk, q);  // B[k][n] = X[n][k], n = col 0..15
      accA = MFMA(av, b0, accA);
      accB = MFMA(av, av, accB);        // diag tile: B-frag == A-frag
    }
    #pragma unroll
    for (int i = 0; i < 4; ++i) {
      gA[(wave * 16 + q * 4 + i) * 17 + c] = accA[i];
      if (c == q * 4 + i) diagS[wave * 16 + q * 4 + i] = accB[i];
    }
  }
  __syncthreads();

  const float ds = delta_s_p[rows[0]];
  const float dt = delta_t_p[rows[1]];
  const float et = e_times[b];
  const float gb0 = gbp[0];

  // attention / gating: wave0 = s-side, wave1 = t-side
  if (wave < 2) {
    const bool is_s = (wave == 0);
    const float dd = is_s ? ds : dt;
    float dval = 0.f, maskv = 0.f, simv = -INFINITY, pav = 0.f, gdot = 0.f;
    if (lane < H_NBRS) {
      int hr = (is_s ? 16 : 36) + lane;
      float ht = is_s ? s_h_times[b * H_NBRS + lane] : t_h_times[b * H_NBRS + lane];
      maskv    = is_s ? s_maskp[b * H_NBRS + lane]   : t_maskp[b * H_NBRS + lane];
      dval = fabsf(et - ht);
      float score = gA[(is_s ? 0 : 1) * 17 + 12] + gA[hr * 17 + 13];
      float x = expf(-ds * dval) * score;  // reference uses ds for BOTH sims
      simv = (x > 0.f) ? x : 0.2f * x;     // leaky_relu 0.2
      int other = is_s ? 1 : 0;
      pav = diagS[hr] + gA[other * 17 + other] - 2.f * gA[hr * 17 + other];
      gdot = gA[hr * 17 + 14];
    }
    float m = wave_max(simv);
    float ev = (lane < H_NBRS) ? expf(simv - m) : 0.f;
    float att = ev / wave_sum(ev);
    float meand = wave_sum(dval) * (1.f / (float)H_NBRS);
    float Eh = expf(dd * dval);
    float cm = att * maskv;
    float P = wave_sum((lane < H_NBRS) ? cm * pav * Eh : 0.f);
    float gsum = wave_sum((lane < H_NBRS) ? cm * gdot : 0.f);
    if (lane < H_NBRS) S[(is_s ? 0 : 20) + lane] = cm * Eh;
    if (lane == 0) {
      S[40 + wave] = P;
      S[42 + wave] = tanhf(expf(-dd * meand) * gsum + gb0);
    }
  }
  __syncthreads();

  // losses (wave 0)
  if (wave == 0) {
    float gls = S[42], glt = S[43];
    float mg = fmaxf(gls, glt);
    float eg_s = expf(gls - mg), eg_t = expf(glt - mg);
    float inv = 1.f / (eg_s + eg_t);
    float ga_s = eg_s * inv, ga_t = eg_t * inv;

    float nl = 0.f;
    if (lane < NEG_K) {  // s-side negatives = neg1, rows 7..11
      int nr = 7 + lane;
      float diag_n = gA[nr * 17 + nr];
      float n_mu = gA[0] + diag_n - 2.f * gA[0 * 17 + nr];
      float acc = 0.f;
      #pragma unroll
      for (int h = 0; h < H_NBRS; ++h)
        acc = fmaf(S[h], diagS[16 + h] + diag_n - 2.f * gA[(16 + h) * 17 + nr], acc);
      float nls = n_mu + ga_s * acc;
      float ns = fmaxf(gA[0 * 17 + nr], 0.f);  // relu(pos0 . neg1[n])
      nl = -logf(1.f / (1.f + expf(nls)) + 1e-6f) * ns * ns;
    } else if (lane < 2 * NEG_K) {  // t-side negatives = neg0, rows 2..6
      int n = lane - NEG_K;
      int nr = 2 + n;
      float diag_n = gA[nr * 17 + nr];
      float n_mu = gA[1 * 17 + 1] + diag_n - 2.f * gA[1 * 17 + nr];
      float acc = 0.f;
      #pragma unroll
      for (int h = 0; h < H_NBRS; ++h)
        acc = fmaf(S[20 + h], diagS[36 + h] + diag_n - 2.f * gA[(36 + h) * 17 + nr], acc);
      float nlt = n_mu + ga_t * acc;
      float ns = fmaxf(gA[1 * 17 + nr], 0.f);  // relu(pos1 . neg0[n])
      nl = -logf(1.f / (1.f + expf(nlt)) + 1e-6f) * ns * ns;
    }
    float nsum = wave_sum(nl);
    if (lane == 0) {
      float p_mu = gA[0] + gA[1 * 17 + 1] - 2.f * gA[1];
      float p_lambda = p_mu + ga_s * S[40] + ga_t * S[41];
      float pos = fmaxf(gA[1], 0.f);
      float pl = -logf(1.f / (1.f + expf(-p_lambda)) + 1e-6f) * (pos - 1.f) * (pos - 1.f);
      atomicAdd(out_loss, pl * (1.f / 4096.f) + nsum * (1.f / (4096.f * 5.f)));
      out_pos[b] = pos;
    }
  }
}

// ---------------------------------------------------------------------------
extern "C" void kernel_launch(void* const* d_in, const int* in_sizes, int n_in,
                              void* d_out, int out_size, void* d_ws, size_t ws_size,
                              hipStream_t stream) {
  const float* nf           = (const float*)d_in[0];
  const int*   sources      = (const int*)d_in[1];
  const int*   destinations = (const int*)d_in[2];
  const float* e_times      = (const float*)d_in[3];
  const int*   s_h_nodes    = (const int*)d_in[4];
  const int*   t_h_nodes    = (const int*)d_in[5];
  const float* s_h_times    = (const float*)d_in[6];
  const float* t_h_times    = (const float*)d_in[7];
  const float* s_mask       = (const float*)d_in[8];
  const float* t_mask       = (const float*)d_in[9];
  const int*   neg_src      = (const int*)d_in[10];
  const int*   neg_dst      = (const int*)d_in[11];
  const float* W1           = (const float*)d_in[12];
  const float* b1           = (const float*)d_in[13];
  const float* W2           = (const float*)d_in[14];
  const float* b2           = (const float*)d_in[15];
  const float* W            = (const float*)d_in[16];
  const float* a            = (const float*)d_in[17];
  const float* delta_s_p    = (const float*)d_in[18];
  const float* delta_t_p    = (const float*)d_in[19];
  const float* gw           = (const float*)d_in[20];
  const float* gb           = (const float*)d_in[21];

  float* out      = (float*)d_out;
  float* out_loss = out;                 // [0]
  float* out_pos  = out + 1;             // [1 .. 4096]
  float* emb      = out + 1 + B_EDGES;   // [4097 ..] node_emb (N*E)

  // ws layout: [embH (N+4 rows bf16, optional)] [w1f 16KB] [w2f 16KB] [wav 1.5KB]
  size_t embH_bytes = (size_t)(N_NODES + 4) * E_DIM * sizeof(unsigned short);
  bool useH = ws_size >= embH_bytes + 2 * 16384 + 3 * E_DIM * sizeof(float) + 256;
  char* p = (char*)d_ws;
  unsigned short* embH = nullptr;
  if (useH) { embH = (unsigned short*)p; p += embH_bytes; }
  unsigned short* w1f = (unsigned short*)p; p += 16384;
  unsigned short* w2f = (unsigned short*)p; p += 16384;
  float*          wav = (float*)p;

  prep_kernel<<<1, 1024, 0, stream>>>(W, a, gw, W1, W2, w1f, w2f, wav, embH, out_loss);
  mlp_kernel<<<N_NODES / 64, 256, 0, stream>>>(nf, w1f, w2f, b1, b2, emb, embH);
  edge_kernel<<<B_EDGES, 256, 0, stream>>>(emb, embH, sources, destinations, e_times,
      s_h_nodes, t_h_nodes, s_h_times, t_h_times, s_mask, t_mask, neg_src, neg_dst,
      wav, delta_s_p, delta_t_p, gb, out_loss, out_pos);
}

// Round 5
// 318.057 us; speedup vs baseline: 1.1832x; 1.1832x over previous
//
#include <hip/hip_runtime.h>
#include <hip/hip_bf16.h>
#include <math.h>

#define N_NODES 200000
#define E_DIM   128
#define B_EDGES 4096
#define H_NBRS  20
#define NEG_K   5
#define HID     60
#define Z_ROW   (N_NODES + 3)   // all-zero bf16 row in embH

typedef short bf16x8 __attribute__((ext_vector_type(8)));
typedef float f32x4  __attribute__((ext_vector_type(4)));

#define MFMA(a, b, c) __builtin_amdgcn_mfma_f32_16x16x32_bf16((a), (b), (c), 0, 0, 0)

__device__ __forceinline__ unsigned short f2b(float f) {  // fp32 -> bf16 RNE
  unsigned u = __float_as_uint(f);
  u += 0x7fffu + ((u >> 16) & 1u);
  return (unsigned short)(u >> 16);
}

__device__ __forceinline__ float wave_sum(float v) {
  #pragma unroll
  for (int m = 1; m < 64; m <<= 1) v += __shfl_xor(v, m, 64);
  return v;
}
__device__ __forceinline__ float wave_max(float v) {
  #pragma unroll
  for (int m = 1; m < 64; m <<= 1) v = fmaxf(v, __shfl_xor(v, m, 64));
  return v;
}

// XOR-swizzled bf16 tile: row stride 128 bf16 (256B); 16B chunk index is
// XORed with (row&3)<<2 so ds_read_b128 A/B-fragment reads spread banks.
__device__ __forceinline__ bf16x8 xfrag(const unsigned short* xS, int m, int kk, int q) {
  int chunk = (kk * 4 + q) ^ ((m & 3) << 2);
  return *(const bf16x8*)(xS + m * 128 + chunk * 8);
}

// ---------------------------------------------------------------------------
// prep: pack W1/W2 into MFMA B-fragment order (bf16); wa1=W@a1, wa2=W@a2,
// wgw=W@gw (f32 + bf16 rows N_NODES..N_NODES+2 of embH, zero row N_NODES+3);
// zero the loss slot.
// ---------------------------------------------------------------------------
__global__ __launch_bounds__(1024) void prep_kernel(
    const float* __restrict__ W, const float* __restrict__ a,
    const float* __restrict__ gw, const float* __restrict__ W1,
    const float* __restrict__ W2, unsigned short* __restrict__ w1f,
    unsigned short* __restrict__ w2f, float* __restrict__ wav,
    unsigned short* __restrict__ embH, float* __restrict__ out_loss) {
  __shared__ float wavS[3 * E_DIM];
  const int tid = threadIdx.x;
  const int lane = tid & 63, grp = tid >> 6;  // 16 groups of 64 lanes
  const int q = lane >> 4, c = lane & 15;

  {  // W1 [128x60] -> frags g = kk*4 + t  (4 ksteps x 4 n-tiles, n padded to 64)
    const int kk = grp >> 2, t = grp & 3;
    const int n = t * 16 + c, k0 = kk * 32 + q * 8;
    unsigned v[4];
    #pragma unroll
    for (int jj = 0; jj < 4; ++jj) {
      unsigned short lo = (n < 60) ? f2b(W1[(k0 + 2 * jj) * 60 + n]) : 0;
      unsigned short hi = (n < 60) ? f2b(W1[(k0 + 2 * jj + 1) * 60 + n]) : 0;
      v[jj] = (unsigned)lo | ((unsigned)hi << 16);
    }
    ((uint4*)w1f)[grp * 64 + lane] = make_uint4(v[0], v[1], v[2], v[3]);
  }
  {  // W2 [60x128] -> frags g = ks*8 + t  (2 ksteps (K padded 60->64) x 8 n-tiles)
    const int ks = grp >> 3, t = grp & 7;
    const int n = t * 16 + c, k0 = ks * 32 + q * 8;
    unsigned v[4];
    #pragma unroll
    for (int jj = 0; jj < 4; ++jj) {
      int k = k0 + 2 * jj;
      unsigned short lo = (k < 60) ? f2b(W2[k * 128 + n]) : 0;
      unsigned short hi = (k + 1 < 60) ? f2b(W2[(k + 1) * 128 + n]) : 0;
      v[jj] = (unsigned)lo | ((unsigned)hi << 16);
    }
    ((uint4*)w2f)[grp * 64 + lane] = make_uint4(v[0], v[1], v[2], v[3]);
  }
  if (tid < 128) {
    const float* row = W + tid * E_DIM;
    float s1 = 0.f, s2 = 0.f, sg = 0.f;
    for (int f = 0; f < E_DIM; ++f) {
      float w = row[f];
      s1 = fmaf(w, a[f], s1);
      s2 = fmaf(w, a[E_DIM + f], s2);
      sg = fmaf(w, gw[f], sg);
    }
    wav[tid] = s1; wav[E_DIM + tid] = s2; wav[2 * E_DIM + tid] = sg;
    wavS[tid] = s1; wavS[E_DIM + tid] = s2; wavS[2 * E_DIM + tid] = sg;
  }
  __syncthreads();
  if (embH && tid < 512) {
    int r = tid >> 7, col = tid & 127;
    embH[(size_t)(N_NODES + r) * E_DIM + col] = (r < 3) ? f2b(wavS[r * E_DIM + col]) : 0;
  }
  if (tid == 0) *out_loss = 0.f;
}

// ---------------------------------------------------------------------------
// MLP via MFMA: emb = relu(nf@W1+b1)@W2+b2. Block = 64 rows, wave = 16 rows.
// Wave-private LDS tiles -> no __syncthreads. Epilogue transposes the MFMA
// C-layout through LDS so global stores are full-line coalesced:
//   f32 emb  -> float4 nontemporal (pure output, keep out of L3)
//   bf16 embH-> ushort8 (16B/lane, 256B rows; L3-resident for edge gathers)
// The transpose tile ALIASES the dead A/hidden tiles (one 8448B/wave buffer).
// ---------------------------------------------------------------------------
__global__ __launch_bounds__(256) void mlp_kernel(
    const float* __restrict__ nf, const unsigned short* __restrict__ w1f,
    const unsigned short* __restrict__ w2f, const float* __restrict__ b1,
    const float* __restrict__ b2, float* __restrict__ emb,
    unsigned short* __restrict__ embH) {
  __shared__ char smem[4][8448];  // per-wave: [aS 4096B ushort16x128][cS 4352B f32 16x68]
                                  // epilogue aliases all 8448B as f32 16x130 tile

  const int tid = threadIdx.x, wave = tid >> 6, lane = tid & 63;
  const int q = lane >> 4, c = lane & 15;
  unsigned short* aw = (unsigned short*)smem[wave];
  float* cw = (float*)(smem[wave] + 4096);
  float* ew = (float*)smem[wave];           // 16 x 130 f32 (aliases aw+cw)
  const size_t R = (size_t)blockIdx.x * 64 + wave * 16;  // 3125*64 == 200000

  // stage 16 rows x 128 f32 -> bf16 swizzled LDS (8 float4 per lane)
  #pragma unroll
  for (int it = 0; it < 8; ++it) {
    int v = it * 64 + lane;          // 0..511
    int r = v >> 5, c4 = v & 31;
    float4 x = *(const float4*)(nf + (R + r) * E_DIM + c4 * 4);
    int chunk = c4 >> 1, half = c4 & 1;
    int phys = r * 128 + (((chunk ^ ((r & 3) << 2))) << 3) + (half << 2);
    *(ushort4*)&aw[phys] = make_ushort4(f2b(x.x), f2b(x.y), f2b(x.z), f2b(x.w));
  }

  // layer 1: C1[16x64] = A[16x128] @ W1[128x64]
  bf16x8 w1[16];
  #pragma unroll
  for (int g = 0; g < 16; ++g) w1[g] = *(const bf16x8*)(w1f + (g * 64 + lane) * 8);

  f32x4 acc1[4] = {};
  #pragma unroll
  for (int kk = 0; kk < 4; ++kk) {
    bf16x8 av = xfrag(aw, c, kk, q);  // A: m = lane&15, k = kk*32 + q*8 + j
    #pragma unroll
    for (int t = 0; t < 4; ++t) acc1[t] = MFMA(av, w1[kk * 4 + t], acc1[t]);
  }
  // bias + relu -> cS (C/D layout: row = q*4+i, col = lane&15 within tile)
  #pragma unroll
  for (int t = 0; t < 4; ++t) {
    int n = t * 16 + c;
    float bv = (n < 60) ? b1[n] : 0.f;
    #pragma unroll
    for (int i = 0; i < 4; ++i)
      cw[(q * 4 + i) * 68 + n] = fmaxf(acc1[t][i] + bv, 0.f);
  }

  // A2 frags from cS: row m = lane&15, k = ks*32 + q*8 + j
  bf16x8 a2[2];
  #pragma unroll
  for (int ks = 0; ks < 2; ++ks) {
    f32x4 r0 = *(const f32x4*)&cw[c * 68 + ks * 32 + q * 8];
    f32x4 r1 = *(const f32x4*)&cw[c * 68 + ks * 32 + q * 8 + 4];
    bf16x8 t8;
    #pragma unroll
    for (int j = 0; j < 4; ++j) {
      t8[j] = (short)f2b(r0[j]);
      t8[4 + j] = (short)f2b(r1[j]);
    }
    a2[ks] = t8;
  }

  // layer 2: emb[16x128] = relu(C1)[16x64] @ W2[64x128]
  bf16x8 w2r[16];
  #pragma unroll
  for (int g = 0; g < 16; ++g) w2r[g] = *(const bf16x8*)(w2f + (g * 64 + lane) * 8);

  f32x4 acc2[8] = {};
  #pragma unroll
  for (int ks = 0; ks < 2; ++ks)
    #pragma unroll
    for (int t = 0; t < 8; ++t) acc2[t] = MFMA(a2[ks], w2r[ks * 8 + t], acc2[t]);

  // ---- epilogue: C-layout -> LDS tile (stride 130), then coalesced stores ----
  #pragma unroll
  for (int t = 0; t < 8; ++t) {
    int n = t * 16 + c;
    float bv = b2[n];
    #pragma unroll
    for (int i = 0; i < 4; ++i)
      ew[(q * 4 + i) * 130 + n] = acc2[t][i] + bv;  // <=2-way bank aliasing
  }
  // f32 out: full rows, float4, nontemporal (never read again; spare L3)
  #pragma unroll
  for (int it = 0; it < 8; ++it) {
    int v = it * 64 + lane;
    int r = v >> 5, c4 = v & 31;
    f32x4 x = *(const f32x4*)&ew[r * 130 + c4 * 4];
    float* dst = emb + (R + r) * E_DIM + c4 * 4;
    __builtin_nontemporal_store(x[0], dst + 0);
    __builtin_nontemporal_store(x[1], dst + 1);
    __builtin_nontemporal_store(x[2], dst + 2);
    __builtin_nontemporal_store(x[3], dst + 3);
  }
  // bf16 out: 16B/lane, 16 lanes cover a full 256B row
  if (embH) {
    #pragma unroll
    for (int it = 0; it < 4; ++it) {
      int v = it * 64 + lane;
      int r = v >> 4, ch = v & 15;
      f32x4 x0 = *(const f32x4*)&ew[r * 130 + ch * 8];
      f32x4 x1 = *(const f32x4*)&ew[r * 130 + ch * 8 + 4];
      ushort4 lo = make_ushort4(f2b(x0[0]), f2b(x0[1]), f2b(x0[2]), f2b(x0[3]));
      ushort4 hi = make_ushort4(f2b(x1[0]), f2b(x1[1]), f2b(x1[2]), f2b(x1[3]));
      unsigned short* dst = embH + (R + r) * E_DIM + ch * 8;
      *(ushort4*)dst = lo;
      *(ushort4*)(dst + 4) = hi;
    }
  }
}

// ---------------------------------------------------------------------------
// Edge kernel: one block per edge. X[64x128] (bf16):
//   0=pos0, 1=pos1, 2..6=neg0, 7..11=neg1, 12=wa1, 13=wa2, 14=wgw, 15=0,
//   16..35=s_h, 36..55=t_h, 56..63=0.
// Only Gram cols 0..15 + diagonals are used: each wave computes its 16x16
// tile vs cols 0..15 (gA, stride 17) and its diagonal tile (MFMA(av,av)).
// S[]: 0..19 c2_s, 20..39 c2_t, 40 P_s, 41 P_t, 42 glogit_s, 43 glogit_t.
// ---------------------------------------------------------------------------
__global__ __launch_bounds__(256) void edge_kernel(
    const float* __restrict__ emb, const unsigned short* __restrict__ embH,
    const int* __restrict__ sources, const int* __restrict__ destinations,
    const float* __restrict__ e_times,
    const int* __restrict__ s_h_nodes, const int* __restrict__ t_h_nodes,
    const float* __restrict__ s_h_times, const float* __restrict__ t_h_times,
    const float* __restrict__ s_maskp, const float* __restrict__ t_maskp,
    const int* __restrict__ neg_src, const int* __restrict__ neg_dst,
    const float* __restrict__ wav,
    const float* __restrict__ delta_s_p, const float* __restrict__ delta_t_p,
    const float* __restrict__ gbp,
    float* __restrict__ out_loss, float* __restrict__ out_pos) {
  __shared__ unsigned short xS[64 * 128];  // 16 KB bf16 swizzled
  __shared__ float gA[64 * 17];            // Gram cols 0..15, stride 17
  __shared__ float diagS[64];
  __shared__ float S[64];
  __shared__ int rows[64];

  const int b = blockIdx.x;
  const int tid = threadIdx.x;
  const int wave = tid >> 6, lane = tid & 63;
  const int q = lane >> 4, c = lane & 15;

  if (tid < 64) {
    int idx = Z_ROW;
    if (tid == 0)       idx = sources[b];
    else if (tid == 1)  idx = destinations[b];
    else if (tid < 7)   idx = neg_src[b * NEG_K + (tid - 2)];
    else if (tid < 12)  idx = neg_dst[b * NEG_K + (tid - 7)];
    else if (tid == 12) idx = N_NODES;
    else if (tid == 13) idx = N_NODES + 1;
    else if (tid == 14) idx = N_NODES + 2;
    else if (tid >= 16 && tid < 36) idx = s_h_nodes[b * H_NBRS + (tid - 16)];
    else if (tid >= 36 && tid < 56) idx = t_h_nodes[b * H_NBRS + (tid - 36)];
    rows[tid] = idx;
  }
  __syncthreads();

  if (embH) {
    // bf16 gather: 64 rows x 256B = 1024 16B-chunks over 256 threads
    #pragma unroll
    for (int it = 0; it < 4; ++it) {
      int v = it * 256 + tid;
      int r = v >> 4, ch = v & 15;
      uint4 u = *(const uint4*)(embH + (size_t)rows[r] * E_DIM + ch * 8);
      int phys = ch ^ ((r & 3) << 2);
      *(uint4*)&xS[r * 128 + phys * 8] = u;
    }
  } else {
    #pragma unroll
    for (int it = 0; it < 8; ++it) {
      int v = it * 256 + tid;
      int r = v >> 5, c4 = v & 31;
      float4 x = make_float4(0.f, 0.f, 0.f, 0.f);
      if (r < 12 || (r >= 16 && r < 56))
        x = *(const float4*)(emb + (size_t)rows[r] * E_DIM + c4 * 4);
      else if (r >= 12 && r < 15)
        x = *(const float4*)(wav + (r - 12) * E_DIM + c4 * 4);
      int chunk = c4 >> 1, half = c4 & 1;
      int phys = r * 128 + ((chunk ^ ((r & 3) << 2)) << 3) + (half << 2);
      *(ushort4*)&xS[phys] = make_ushort4(f2b(x.x), f2b(x.y), f2b(x.z), f2b(x.w));
    }
  }
  __syncthreads();

  // Gram: wave w -> rows [16w,16w+16) x cols [0,16) (accA) + own diag (accB)
  {
    f32x4 accA = {0.f, 0.f, 0.f, 0.f};
    f32x4 accB = {0.f, 0.f, 0.f, 0.f};
    #pragma unroll
    for (int kk = 0; kk < 4; ++kk) {
      bf16x8 av = xfrag(xS, wave * 16 + c, kk, q);
      bf16x8 b0 = xfrag(xS, c, kk, q);  // B[k][n] = X[n][k], n = col 0..15
      accA = MFMA(av, b0, accA);
      accB = MFMA(av, av, accB);        // diag tile: B-frag == A-frag
    }
    #pragma unroll
    for (int i = 0; i < 4; ++i) {
      gA[(wave * 16 + q * 4 + i) * 17 + c] = accA[i];
      if (c == q * 4 + i) diagS[wave * 16 + q * 4 + i] = accB[i];
    }
  }
  __syncthreads();

  const float ds = delta_s_p[rows[0]];
  const float dt = delta_t_p[rows[1]];
  const float et = e_times[b];
  const float gb0 = gbp[0];

  // attention / gating: wave0 = s-side, wave1 = t-side
  if (wave < 2) {
    const bool is_s = (wave == 0);
    const float dd = is_s ? ds : dt;
    float dval = 0.f, maskv = 0.f, simv = -INFINITY, pav = 0.f, gdot = 0.f;
    if (lane < H_NBRS) {
      int hr = (is_s ? 16 : 36) + lane;
      float ht = is_s ? s_h_times[b * H_NBRS + lane] : t_h_times[b * H_NBRS + lane];
      maskv    = is_s ? s_maskp[b * H_NBRS + lane]   : t_maskp[b * H_NBRS + lane];
      dval = fabsf(et - ht);
      float score = gA[(is_s ? 0 : 1) * 17 + 12] + gA[hr * 17 + 13];
      float x = expf(-ds * dval) * score;  // reference uses ds for BOTH sims
      simv = (x > 0.f) ? x : 0.2f * x;     // leaky_relu 0.2
      int other = is_s ? 1 : 0;
      pav = diagS[hr] + gA[other * 17 + other] - 2.f * gA[hr * 17 + other];
      gdot = gA[hr * 17 + 14];
    }
    float m = wave_max(simv);
    float ev = (lane < H_NBRS) ? expf(simv - m) : 0.f;
    float att = ev / wave_sum(ev);
    float meand = wave_sum(dval) * (1.f / (float)H_NBRS);
    float Eh = expf(dd * dval);
    float cm = att * maskv;
    float P = wave_sum((lane < H_NBRS) ? cm * pav * Eh : 0.f);
    float gsum = wave_sum((lane < H_NBRS) ? cm * gdot : 0.f);
    if (lane < H_NBRS) S[(is_s ? 0 : 20) + lane] = cm * Eh;
    if (lane == 0) {
      S[40 + wave] = P;
      S[42 + wave] = tanhf(expf(-dd * meand) * gsum + gb0);
    }
  }
  __syncthreads();

  // losses (wave 0)
  if (wave == 0) {
    float gls = S[42], glt = S[43];
    float mg = fmaxf(gls, glt);
    float eg_s = expf(gls - mg), eg_t = expf(glt - mg);
    float inv = 1.f / (eg_s + eg_t);
    float ga_s = eg_s * inv, ga_t = eg_t * inv;

    float nl = 0.f;
    if (lane < NEG_K) {  // s-side negatives = neg1, rows 7..11
      int nr = 7 + lane;
      float diag_n = gA[nr * 17 + nr];
      float n_mu = gA[0] + diag_n - 2.f * gA[0 * 17 + nr];
      float acc = 0.f;
      #pragma unroll
      for (int h = 0; h < H_NBRS; ++h)
        acc = fmaf(S[h], diagS[16 + h] + diag_n - 2.f * gA[(16 + h) * 17 + nr], acc);
      float nls = n_mu + ga_s * acc;
      float ns = fmaxf(gA[0 * 17 + nr], 0.f);  // relu(pos0 . neg1[n])
      nl = -logf(1.f / (1.f + expf(nls)) + 1e-6f) * ns * ns;
    } else if (lane < 2 * NEG_K) {  // t-side negatives = neg0, rows 2..6
      int n = lane - NEG_K;
      int nr = 2 + n;
      float diag_n = gA[nr * 17 + nr];
      float n_mu = gA[1 * 17 + 1] + diag_n - 2.f * gA[1 * 17 + nr];
      float acc = 0.f;
      #pragma unroll
      for (int h = 0; h < H_NBRS; ++h)
        acc = fmaf(S[20 + h], diagS[36 + h] + diag_n - 2.f * gA[(36 + h) * 17 + nr], acc);
      float nlt = n_mu + ga_t * acc;
      float ns = fmaxf(gA[1 * 17 + nr], 0.f);  // relu(pos1 . neg0[n])
      nl = -logf(1.f / (1.f + expf(nlt)) + 1e-6f) * ns * ns;
    }
    float nsum = wave_sum(nl);
    if (lane == 0) {
      float p_mu = gA[0] + gA[1 * 17 + 1] - 2.f * gA[1];
      float p_lambda = p_mu + ga_s * S[40] + ga_t * S[41];
      float pos = fmaxf(gA[1], 0.f);
      float pl = -logf(1.f / (1.f + expf(-p_lambda)) + 1e-6f) * (pos - 1.f) * (pos - 1.f);
      atomicAdd(out_loss, pl * (1.f / 4096.f) + nsum * (1.f / (4096.f * 5.f)));
      out_pos[b] = pos;
    }
  }
}

// ---------------------------------------------------------------------------
extern "C" void kernel_launch(void* const* d_in, const int* in_sizes, int n_in,
                              void* d_out, int out_size, void* d_ws, size_t ws_size,
                              hipStream_t stream) {
  const float* nf           = (const float*)d_in[0];
  const int*   sources      = (const int*)d_in[1];
  const int*   destinations = (const int*)d_in[2];
  const float* e_times      = (const float*)d_in[3];
  const int*   s_h_nodes    = (const int*)d_in[4];
  const int*   t_h_nodes    = (const int*)d_in[5];
  const float* s_h_times    = (const float*)d_in[6];
  const float* t_h_times    = (const float*)d_in[7];
  const float* s_mask       = (const float*)d_in[8];
  const float* t_mask       = (const float*)d_in[9];
  const int*   neg_src      = (const int*)d_in[10];
  const int*   neg_dst      = (const int*)d_in[11];
  const float* W1           = (const float*)d_in[12];
  const float* b1           = (const float*)d_in[13];
  const float* W2           = (const float*)d_in[14];
  const float* b2           = (const float*)d_in[15];
  const float* W            = (const float*)d_in[16];
  const float* a            = (const float*)d_in[17];
  const float* delta_s_p    = (const float*)d_in[18];
  const float* delta_t_p    = (const float*)d_in[19];
  const float* gw           = (const float*)d_in[20];
  const float* gb           = (const float*)d_in[21];

  float* out      = (float*)d_out;
  float* out_loss = out;                 // [0]
  float* out_pos  = out + 1;             // [1 .. 4096]
  float* emb      = out + 1 + B_EDGES;   // [4097 ..] node_emb (N*E)

  // ws layout: [embH (N+4 rows bf16, optional)] [w1f 16KB] [w2f 16KB] [wav 1.5KB]
  size_t embH_bytes = (size_t)(N_NODES + 4) * E_DIM * sizeof(unsigned short);
  bool useH = ws_size >= embH_bytes + 2 * 16384 + 3 * E_DIM * sizeof(float) + 256;
  char* p = (char*)d_ws;
  unsigned short* embH = nullptr;
  if (useH) { embH = (unsigned short*)p; p += embH_bytes; }
  unsigned short* w1f = (unsigned short*)p; p += 16384;
  unsigned short* w2f = (unsigned short*)p; p += 16384;
  float*          wav = (float*)p;

  prep_kernel<<<1, 1024, 0, stream>>>(W, a, gw, W1, W2, w1f, w2f, wav, embH, out_loss);
  mlp_kernel<<<N_NODES / 64, 256, 0, stream>>>(nf, w1f, w2f, b1, b2, emb, embH);
  edge_kernel<<<B_EDGES, 256, 0, stream>>>(emb, embH, sources, destinations, e_times,
      s_h_nodes, t_h_nodes, s_h_times, t_h_times, s_mask, t_mask, neg_src, neg_dst,
      wav, delta_s_p, delta_t_p, gb, out_loss, out_pos);
}